// Round 2
// baseline (289.121 us; speedup 1.0000x reference)
//
#include <hip/hip_runtime.h>
#include <hip/hip_bf16.h>

#define N 1024
#define D 128

// ---------------- Kernel A: Q,K,a,b projections (biases folded) ----------------
__global__ __launch_bounds__(128) void proj_kernel(
    const float* __restrict__ z,
    const float* __restrict__ Wq, const float* __restrict__ bq,
    const float* __restrict__ Wk, const float* __restrict__ bk,
    const float* __restrict__ W1, const float* __restrict__ b1,
    float* __restrict__ Q, float* __restrict__ Kx,
    float* __restrict__ A, float* __restrict__ B)
{
    const int i = blockIdx.x;
    const int d = threadIdx.x;
    __shared__ float zrow[D];
    zrow[d] = z[i * D + d];
    __syncthreads();
    float q = 0.f, k = 0.f, a = 0.f, b = 0.f;
#pragma unroll 8
    for (int t = 0; t < D; ++t) {
        const float zv = zrow[t];
        q = fmaf(zv, Wq[t * D + d], q);
        k = fmaf(zv, Wk[t * D + d], k);
        a = fmaf(zv, W1[t * D + d], a);
        b = fmaf(zv, W1[(D + t) * D + d], b);
    }
    Q[i * D + d]  = q + bq[d];
    Kx[i * D + d] = k + bk[d];
    A[i * D + d]  = a + b1[d];   // fold b1 into a-half
    B[i * D + d]  = b;
}

// ---------------- Kernel B: attention row: scores, softmax, top-32 ----------------
__global__ __launch_bounds__(256) void attn_kernel(
    const float* __restrict__ Q, const float* __restrict__ Kx,
    const float* __restrict__ dist, float* __restrict__ adj)
{
    const int i   = blockIdx.x;
    const int tid = threadIdx.x;   // 256 threads = 4 waves
    __shared__ float qrow[D];
    __shared__ float s[N];         // scores
    __shared__ float w[N];         // destructible copy for selection
    __shared__ float red[256];
    __shared__ float rv[4];
    __shared__ int   ri[4];
    __shared__ unsigned char flag[N];

    if (tid < D) qrow[tid] = Q[i * D + tid];
    __syncthreads();

    const float scale = 0.08838834764831845f;  // 1/sqrt(128), TEMPERATURE=1
    for (int j = tid; j < N; j += 256) {
        const float* kr = Kx + (size_t)j * D;
        float acc = 0.f;
#pragma unroll 8
        for (int t = 0; t < D; ++t) acc = fmaf(qrow[t], kr[t], acc);
        const float v = acc * scale * expf(-dist[(size_t)i * N + j]);
        s[j] = v; w[j] = v; flag[j] = 0;
    }
    __syncthreads();

    // row max
    float lm = -INFINITY;
    for (int j = tid; j < N; j += 256) lm = fmaxf(lm, s[j]);
    red[tid] = lm; __syncthreads();
    for (int off = 128; off > 0; off >>= 1) {
        if (tid < off) red[tid] = fmaxf(red[tid], red[tid + off]);
        __syncthreads();
    }
    const float m = red[0];
    __syncthreads();

    // row sum of exp
    float lsum = 0.f;
    for (int j = tid; j < N; j += 256) lsum += expf(s[j] - m);
    red[tid] = lsum; __syncthreads();
    for (int off = 128; off > 0; off >>= 1) {
        if (tid < off) red[tid] += red[tid + off];
        __syncthreads();
    }
    const float inv_sum = 1.0f / red[0];

    // top-32 via repeated argmax (stable: ties -> smallest index, matches lax.top_k)
    const int lane = tid & 63;
    const int wv   = tid >> 6;
    for (int it = 0; it < 32; ++it) {
        float bv = -INFINITY; int bi = N;
        for (int j = tid; j < N; j += 256) {
            const float v = w[j];
            if (v > bv) { bv = v; bi = j; }   // j ascending: keeps smallest idx on tie
        }
#pragma unroll
        for (int off = 32; off > 0; off >>= 1) {
            const float ov = __shfl_down(bv, off);
            const int   oi = __shfl_down(bi, off);
            if (ov > bv || (ov == bv && oi < bi)) { bv = ov; bi = oi; }
        }
        if (lane == 0) { rv[wv] = bv; ri[wv] = bi; }
        __syncthreads();
        if (tid == 0) {
            float fv = rv[0]; int fi = ri[0];
            for (int u = 1; u < 4; ++u)
                if (rv[u] > fv || (rv[u] == fv && ri[u] < fi)) { fv = rv[u]; fi = ri[u]; }
            flag[fi] = 1; w[fi] = -INFINITY;
        }
        __syncthreads();
    }

    for (int j = tid; j < N; j += 256) {
        const float p = flag[j] ? expf(s[j] - m) * inv_sum : 0.f;
        adj[(size_t)i * N + j] = p;
    }
}

// ---------------- Kernel C: pairwise gelu classifier + 3-way softmax ----------------
__global__ __launch_bounds__(256) void pair_kernel(
    const float* __restrict__ A, const float* __restrict__ B,
    const float* __restrict__ W2, const float* __restrict__ b2,
    float* __restrict__ out)
{
    const int bi  = blockIdx.y * 8;    // 8 i-rows per block
    const int bj  = blockIdx.x * 32;   // 32 j-cols per block
    const int tid = threadIdx.x;
    const int tj  = tid & 31;
    const int ti  = tid >> 5;
    __shared__ float As[8][D + 1];
    __shared__ float Bs[32][D + 1];
    __shared__ float w0[D], w1[D], w2[D];

    for (int t = tid; t < 8 * D; t += 256)
        As[t >> 7][t & 127] = A[(size_t)(bi + (t >> 7)) * D + (t & 127)];
    for (int t = tid; t < 32 * D; t += 256)
        Bs[t >> 7][t & 127] = B[(size_t)(bj + (t >> 7)) * D + (t & 127)];
    for (int t = tid; t < D; t += 256) {
        w0[t] = W2[t * 3 + 0];
        w1[t] = W2[t * 3 + 1];
        w2[t] = W2[t * 3 + 2];
    }
    __syncthreads();

    float l0 = b2[0], l1 = b2[1], l2 = b2[2];
    const float inv_sqrt2 = 0.70710678118654752440f;
#pragma unroll 4
    for (int d = 0; d < D; ++d) {
        const float x = As[ti][d] + Bs[tj][d];
        const float g = 0.5f * x * (1.0f + erff(x * inv_sqrt2));  // exact gelu
        l0 = fmaf(g, w0[d], l0);
        l1 = fmaf(g, w1[d], l1);
        l2 = fmaf(g, w2[d], l2);
    }
    const float mm = fmaxf(l0, fmaxf(l1, l2));
    const float e0 = expf(l0 - mm), e1 = expf(l1 - mm), e2 = expf(l2 - mm);
    const float inv = 1.0f / (e0 + e1 + e2);
    const size_t base = ((size_t)(bi + ti) * N + (bj + tj)) * 3;
    out[base + 0] = e0 * inv;
    out[base + 1] = e1 * inv;
    out[base + 2] = e2 * inv;
}

extern "C" void kernel_launch(void* const* d_in, const int* in_sizes, int n_in,
                              void* d_out, int out_size, void* d_ws, size_t ws_size,
                              hipStream_t stream)
{
    const float* z    = (const float*)d_in[0];
    const float* dist = (const float*)d_in[1];
    const float* Wq   = (const float*)d_in[2];
    const float* bq   = (const float*)d_in[3];
    const float* Wk   = (const float*)d_in[4];
    const float* bk   = (const float*)d_in[5];
    const float* W1   = (const float*)d_in[6];
    const float* b1   = (const float*)d_in[7];
    const float* W2   = (const float*)d_in[8];
    const float* b2   = (const float*)d_in[9];

    float* out = (float*)d_out;
    float* ws = (float*)d_ws;
    float* Q  = ws;
    float* K  = ws + (size_t)N * D;
    float* A  = ws + 2 * (size_t)N * D;
    float* B  = ws + 3 * (size_t)N * D;

    proj_kernel<<<N, D, 0, stream>>>(z, Wq, bq, Wk, bk, W1, b1, Q, K, A, B);
    attn_kernel<<<N, 256, 0, stream>>>(Q, K, dist, out);
    pair_kernel<<<dim3(N / 32, N / 8), 256, 0, stream>>>(A, B, W2, b2, out + (size_t)N * N);
}

// Round 3
// 167.205 us; speedup vs baseline: 1.7291x; 1.7291x over previous
//
#include <hip/hip_runtime.h>

#define N 1024
#define D 128

// ---------------- proj: Q,K,A,B = z@{Wq,Wk,W1a,W1b} (+biases, b1 folded into A) ----------------
__global__ __launch_bounds__(256) void proj_kernel(
    const float* __restrict__ z,
    const float* __restrict__ Wq, const float* __restrict__ bq,
    const float* __restrict__ Wk, const float* __restrict__ bk,
    const float* __restrict__ W1, const float* __restrict__ b1,
    float* __restrict__ Q, float* __restrict__ Kx,
    float* __restrict__ A, float* __restrict__ B)
{
    const int d  = threadIdx.x & (D - 1);
    const int h  = threadIdx.x >> 7;              // wave-uniform: 0 -> Q/K, 1 -> A/B
    const int r0 = blockIdx.x * 8;
    const float* __restrict__ Wa = h ? W1           : Wq;
    const float* __restrict__ Wb = h ? (W1 + D * D) : Wk;

    float acc0[8] = {0,0,0,0,0,0,0,0};
    float acc1[8] = {0,0,0,0,0,0,0,0};

    for (int c = 0; c < D / 4; ++c) {
        float4 zr[8];
#pragma unroll
        for (int r = 0; r < 8; ++r)
            zr[r] = *(const float4*)&z[(r0 + r) * D + c * 4];   // uniform addr -> s_load_dwordx4
#pragma unroll
        for (int q = 0; q < 4; ++q) {
            const int k = c * 4 + q;
            const float wa = Wa[k * D + d];
            const float wb = Wb[k * D + d];
#pragma unroll
            for (int r = 0; r < 8; ++r) {
                const float zv = (q == 0) ? zr[r].x : (q == 1) ? zr[r].y : (q == 2) ? zr[r].z : zr[r].w;
                acc0[r] = fmaf(zv, wa, acc0[r]);
                acc1[r] = fmaf(zv, wb, acc1[r]);
            }
        }
    }
    if (h == 0) {
        const float c0 = bq[d], c1 = bk[d];
#pragma unroll
        for (int r = 0; r < 8; ++r) {
            Q [(r0 + r) * D + d] = acc0[r] + c0;
            Kx[(r0 + r) * D + d] = acc1[r] + c1;
        }
    } else {
        const float c0 = b1[d];
#pragma unroll
        for (int r = 0; r < 8; ++r) {
            A[(r0 + r) * D + d] = acc0[r] + c0;
            B[(r0 + r) * D + d] = acc1[r];
        }
    }
}

// ---------------- scores: S = (Q K^T) * scale * exp(-dist), tiled 64x64 ----------------
__global__ __launch_bounds__(256) void score_kernel(
    const float* __restrict__ Q, const float* __restrict__ Kx,
    const float* __restrict__ dist, float* __restrict__ S)
{
    __shared__ float Qs[64 * 64];
    __shared__ float Ks[64 * 64];
    const int tid = threadIdx.x;
    const int bi = blockIdx.y * 64, bj = blockIdx.x * 64;
    const int tx = tid & 15, ty = tid >> 4;
    float acc[4][4] = {};
    const float4* Qs4 = (const float4*)Qs;
    const float4* Ks4 = (const float4*)Ks;

    for (int kk = 0; kk < D; kk += 64) {
#pragma unroll
        for (int t = 0; t < 4; ++t) {
            const int e   = t * 256 + tid;      // 0..1023: 64 rows x 16 float4-chunks
            const int row = e >> 4, c = e & 15;
            const int sw  = ((c + row) & 15) * 4;    // XOR-ish swizzle breaks row-stride conflicts
            *(float4*)&Qs[row * 64 + sw] = *(const float4*)&Q [(size_t)(bi + row) * D + kk + c * 4];
            *(float4*)&Ks[row * 64 + sw] = *(const float4*)&Kx[(size_t)(bj + row) * D + kk + c * 4];
        }
        __syncthreads();
#pragma unroll 4
        for (int c = 0; c < 16; ++c) {
            float4 qa[4], kb[4];
#pragma unroll
            for (int a = 0; a < 4; ++a) {
                const int r = 4 * ty + a;
                qa[a] = Qs4[r * 16 + ((c + r) & 15)];
            }
#pragma unroll
            for (int b = 0; b < 4; ++b) {
                const int r = 4 * tx + b;
                kb[b] = Ks4[r * 16 + ((c + r) & 15)];
            }
#pragma unroll
            for (int a = 0; a < 4; ++a)
#pragma unroll
                for (int b = 0; b < 4; ++b) {
                    acc[a][b] = fmaf(qa[a].x, kb[b].x, acc[a][b]);
                    acc[a][b] = fmaf(qa[a].y, kb[b].y, acc[a][b]);
                    acc[a][b] = fmaf(qa[a].z, kb[b].z, acc[a][b]);
                    acc[a][b] = fmaf(qa[a].w, kb[b].w, acc[a][b]);
                }
        }
        __syncthreads();
    }

    const float scale = 0.08838834764831845f;   // 1/sqrt(128)
#pragma unroll
    for (int a = 0; a < 4; ++a) {
        const int i  = bi + 4 * ty + a;
        const int j0 = bj + 4 * tx;
        const float4 dd = *(const float4*)&dist[(size_t)i * N + j0];
        float4 o;
        o.x = acc[a][0] * scale * __expf(-dd.x);
        o.y = acc[a][1] * scale * __expf(-dd.y);
        o.z = acc[a][2] * scale * __expf(-dd.z);
        o.w = acc[a][3] * scale * __expf(-dd.w);
        *(float4*)&S[(size_t)i * N + j0] = o;
    }
}

// ---------------- softmax + top-32 per row; one wave per row, no barriers ----------------
__global__ __launch_bounds__(256) void topk_kernel(float* buf /* in: scores, out: adjacency (in-place) */)
{
    const int lane = threadIdx.x & 63;
    const int row  = blockIdx.x * 4 + (threadIdx.x >> 6);
    float* sr = buf + (size_t)row * N;

    float v[16];
#pragma unroll
    for (int c = 0; c < 4; ++c) {
        const float4 f = *(const float4*)&sr[(c * 64 + lane) * 4];
        v[c * 4 + 0] = f.x; v[c * 4 + 1] = f.y; v[c * 4 + 2] = f.z; v[c * 4 + 3] = f.w;
    }
    // row max
    float m = v[0];
#pragma unroll
    for (int e = 1; e < 16; ++e) m = fmaxf(m, v[e]);
#pragma unroll
    for (int off = 1; off < 64; off <<= 1) m = fmaxf(m, __shfl_xor(m, off));
    // row sum of exp
    float sum = 0.f;
#pragma unroll
    for (int e = 0; e < 16; ++e) sum += __expf(v[e] - m);
#pragma unroll
    for (int off = 1; off < 64; off <<= 1) sum += __shfl_xor(sum, off);
    const float inv = 1.0f / sum;

    // 64-bit keys: monotonic-float high word, inverted index low word (ties -> smallest j, = lax.top_k)
    unsigned long long key[16];
#pragma unroll
    for (int e = 0; e < 16; ++e) {
        const int j = (( (e >> 2) * 64 + lane) * 4) + (e & 3);
        unsigned u = __float_as_uint(v[e]);
        u = (u & 0x80000000u) ? ~u : (u | 0x80000000u);
        key[e] = ((unsigned long long)u << 32) | (unsigned)(N - 1 - j);
    }
    unsigned flags = 0;
    for (int it = 0; it < 32; ++it) {
        unsigned long long best = key[0];
#pragma unroll
        for (int e = 1; e < 16; ++e) best = (key[e] > best) ? key[e] : best;
#pragma unroll
        for (int off = 1; off < 64; off <<= 1) {
            const unsigned long long o = __shfl_xor(best, off);
            if (o > best) best = o;
        }
#pragma unroll
        for (int e = 0; e < 16; ++e)
            if (key[e] == best) { flags |= 1u << e; key[e] = 0ull; }
    }
#pragma unroll
    for (int c = 0; c < 4; ++c) {
        float4 o;
        o.x = (flags & (1u << (c * 4 + 0))) ? __expf(v[c * 4 + 0] - m) * inv : 0.f;
        o.y = (flags & (1u << (c * 4 + 1))) ? __expf(v[c * 4 + 1] - m) * inv : 0.f;
        o.z = (flags & (1u << (c * 4 + 2))) ? __expf(v[c * 4 + 2] - m) * inv : 0.f;
        o.w = (flags & (1u << (c * 4 + 3))) ? __expf(v[c * 4 + 3] - m) * inv : 0.f;
        *(float4*)&sr[(c * 64 + lane) * 4] = o;
    }
}

// ---------------- pairwise gelu classifier + 3-way softmax ----------------
__device__ __forceinline__ float fast_gelu(float x) {
    // x * sigmoid(1.5957691216*x + 0.0713548163*x^3), exp2-form; max |err| vs exact gelu ~3e-4
    const float u = x * x;
    const float t = x * fmaf(-0.1029434f, u, -2.3022082f);   // -log2(e)*2*inner
    return x * __builtin_amdgcn_rcpf(1.0f + __builtin_amdgcn_exp2f(t));
}

__global__ __launch_bounds__(256) void pair_kernel(
    const float* __restrict__ A, const float* __restrict__ B,
    const float* __restrict__ W2, const float* __restrict__ b2,
    float* __restrict__ out)
{
    __shared__ float As[16 * 128];
    __shared__ float Bs[64 * 128];
    const int tid = threadIdx.x;
    const int bi = blockIdx.y * 16, bj = blockIdx.x * 64;
    const int tx = tid & 31, ty = tid >> 5;

#pragma unroll
    for (int t = 0; t < 2; ++t) {
        const int e = t * 256 + tid;            // 16 rows x 32 chunks
        const int row = e >> 5, c = e & 31;
        *(float4*)&As[row * 128 + ((c + row) & 31) * 4] =
            *(const float4*)&A[(size_t)(bi + row) * D + c * 4];
    }
#pragma unroll
    for (int t = 0; t < 8; ++t) {
        const int e = t * 256 + tid;            // 64 rows x 32 chunks
        const int row = e >> 5, c = e & 31;
        *(float4*)&Bs[row * 128 + ((c + row) & 31) * 4] =
            *(const float4*)&B[(size_t)(bj + row) * D + c * 4];
    }
    const float bb0 = b2[0], bb1 = b2[1], bb2 = b2[2];
    __syncthreads();

    float l[4][3];
#pragma unroll
    for (int p = 0; p < 4; ++p) { l[p][0] = bb0; l[p][1] = bb1; l[p][2] = bb2; }

    const float4* As4 = (const float4*)As;
    const float4* Bs4 = (const float4*)Bs;
    const int r0 = ty, r1 = ty + 8, s0 = tx, s1 = tx + 32;

    for (int c = 0; c < 32; ++c) {
        const float4 a0 = As4[r0 * 32 + ((c + r0) & 31)];
        const float4 a1 = As4[r1 * 32 + ((c + r1) & 31)];
        const float4 b0 = Bs4[s0 * 32 + ((c + s0) & 31)];
        const float4 b1 = Bs4[s1 * 32 + ((c + s1) & 31)];
#pragma unroll
        for (int q = 0; q < 4; ++q) {
            const int dd = c * 4 + q;
            const float w0 = W2[dd * 3 + 0];    // uniform -> s_load via K$
            const float w1 = W2[dd * 3 + 1];
            const float w2 = W2[dd * 3 + 2];
            const float av0 = (q == 0) ? a0.x : (q == 1) ? a0.y : (q == 2) ? a0.z : a0.w;
            const float av1 = (q == 0) ? a1.x : (q == 1) ? a1.y : (q == 2) ? a1.z : a1.w;
            const float bv0 = (q == 0) ? b0.x : (q == 1) ? b0.y : (q == 2) ? b0.z : b0.w;
            const float bv1 = (q == 0) ? b1.x : (q == 1) ? b1.y : (q == 2) ? b1.z : b1.w;
            const float g00 = fast_gelu(av0 + bv0);
            const float g01 = fast_gelu(av0 + bv1);
            const float g10 = fast_gelu(av1 + bv0);
            const float g11 = fast_gelu(av1 + bv1);
            l[0][0] = fmaf(g00, w0, l[0][0]); l[0][1] = fmaf(g00, w1, l[0][1]); l[0][2] = fmaf(g00, w2, l[0][2]);
            l[1][0] = fmaf(g01, w0, l[1][0]); l[1][1] = fmaf(g01, w1, l[1][1]); l[1][2] = fmaf(g01, w2, l[1][2]);
            l[2][0] = fmaf(g10, w0, l[2][0]); l[2][1] = fmaf(g10, w1, l[2][1]); l[2][2] = fmaf(g10, w2, l[2][2]);
            l[3][0] = fmaf(g11, w0, l[3][0]); l[3][1] = fmaf(g11, w1, l[3][1]); l[3][2] = fmaf(g11, w2, l[3][2]);
        }
    }
#pragma unroll
    for (int p = 0; p < 4; ++p) {
        const int i = bi + ((p & 2) ? r1 : r0);
        const int j = bj + ((p & 1) ? s1 : s0);
        const float mm = fmaxf(l[p][0], fmaxf(l[p][1], l[p][2]));
        const float e0 = __expf(l[p][0] - mm), e1 = __expf(l[p][1] - mm), e2 = __expf(l[p][2] - mm);
        const float inv2 = 1.0f / (e0 + e1 + e2);
        float* o = out + ((size_t)i * N + j) * 3;
        o[0] = e0 * inv2; o[1] = e1 * inv2; o[2] = e2 * inv2;
    }
}

extern "C" void kernel_launch(void* const* d_in, const int* in_sizes, int n_in,
                              void* d_out, int out_size, void* d_ws, size_t ws_size,
                              hipStream_t stream)
{
    const float* z    = (const float*)d_in[0];
    const float* dist = (const float*)d_in[1];
    const float* Wq   = (const float*)d_in[2];
    const float* bq   = (const float*)d_in[3];
    const float* Wk   = (const float*)d_in[4];
    const float* bk   = (const float*)d_in[5];
    const float* W1   = (const float*)d_in[6];
    const float* b1   = (const float*)d_in[7];
    const float* W2   = (const float*)d_in[8];
    const float* b2   = (const float*)d_in[9];

    float* out = (float*)d_out;
    float* ws  = (float*)d_ws;
    float* Q  = ws;
    float* K  = ws + (size_t)N * D;
    float* A  = ws + 2 * (size_t)N * D;
    float* B  = ws + 3 * (size_t)N * D;

    proj_kernel<<<N / 8, 256, 0, stream>>>(z, Wq, bq, Wk, bk, W1, b1, Q, K, A, B);
    // scores written into the adjacency region of d_out, then sparsified in-place
    score_kernel<<<dim3(N / 64, N / 64), 256, 0, stream>>>(Q, K, dist, out);
    topk_kernel<<<N / 4, 256, 0, stream>>>(out);
    pair_kernel<<<dim3(N / 64, N / 16), 256, 0, stream>>>(A, B, W2, b2, out + (size_t)N * N);
}

// Round 4
// 167.202 us; speedup vs baseline: 1.7292x; 1.0000x over previous
//
#include <hip/hip_runtime.h>

#define N 1024
#define D 128

// ---------------- proj: Q,K,A,B = z@{Wq,Wk,W1a,W1b} (+biases; b1 folded into A; 1/sqrt(D) folded into Q) ----------------
__global__ __launch_bounds__(256) void proj_kernel(
    const float* __restrict__ z,
    const float* __restrict__ Wq, const float* __restrict__ bq,
    const float* __restrict__ Wk, const float* __restrict__ bk,
    const float* __restrict__ W1, const float* __restrict__ b1,
    float* __restrict__ Q, float* __restrict__ Kx,
    float* __restrict__ A, float* __restrict__ B)
{
    const int d  = threadIdx.x & (D - 1);
    const int h  = threadIdx.x >> 7;              // wave-uniform: 0 -> Q/K, 1 -> A/B
    const int r0 = blockIdx.x * 8;
    const float* __restrict__ Wa = h ? W1           : Wq;
    const float* __restrict__ Wb = h ? (W1 + D * D) : Wk;

    float acc0[8] = {0,0,0,0,0,0,0,0};
    float acc1[8] = {0,0,0,0,0,0,0,0};

    for (int c = 0; c < D / 4; ++c) {
        float4 zr[8];
#pragma unroll
        for (int r = 0; r < 8; ++r)
            zr[r] = *(const float4*)&z[(r0 + r) * D + c * 4];   // uniform addr -> scalar loads
#pragma unroll
        for (int q = 0; q < 4; ++q) {
            const int k = c * 4 + q;
            const float wa = Wa[k * D + d];
            const float wb = Wb[k * D + d];
#pragma unroll
            for (int r = 0; r < 8; ++r) {
                const float zv = (q == 0) ? zr[r].x : (q == 1) ? zr[r].y : (q == 2) ? zr[r].z : zr[r].w;
                acc0[r] = fmaf(zv, wa, acc0[r]);
                acc1[r] = fmaf(zv, wb, acc1[r]);
            }
        }
    }
    if (h == 0) {
        const float c0 = bq[d], c1 = bk[d];
        const float scale = 0.08838834764831845f;   // 1/sqrt(128), folded into Q
#pragma unroll
        for (int r = 0; r < 8; ++r) {
            Q [(r0 + r) * D + d] = (acc0[r] + c0) * scale;
            Kx[(r0 + r) * D + d] = acc1[r] + c1;
        }
    } else {
        const float c0 = b1[d];
#pragma unroll
        for (int r = 0; r < 8; ++r) {
            A[(r0 + r) * D + d] = acc0[r] + c0;
            B[(r0 + r) * D + d] = acc1[r];
        }
    }
}

// ---------------- scores: S = (Q K^T) * exp(-dist), 32x32 tile, whole K staged once ----------------
// LDS pitch 33 float4s: addresses linear in c (no per-read swizzle math); bank aliasing is free 2-way.
__global__ __launch_bounds__(256) void score_kernel(
    const float* __restrict__ Q, const float* __restrict__ Kx,
    const float* __restrict__ dist, float* __restrict__ S)
{
    __shared__ float Qs[32 * 33 * 4];
    __shared__ float Ks[32 * 33 * 4];
    const int tid = threadIdx.x;
    const int bi = blockIdx.y * 32, bj = blockIdx.x * 32;
    const int tx = tid & 15, ty = tid >> 4;

#pragma unroll
    for (int t = 0; t < 4; ++t) {
        const int e = t * 256 + tid;           // 1024 chunks: 32 rows x 32 float4-cols
        const int row = e >> 5, c = e & 31;
        *(float4*)&Qs[(row * 33 + c) * 4] = *(const float4*)&Q [(size_t)(bi + row) * D + c * 4];
        *(float4*)&Ks[(row * 33 + c) * 4] = *(const float4*)&Kx[(size_t)(bj + row) * D + c * 4];
    }
    __syncthreads();

    const float4* Qs4 = (const float4*)Qs;
    const float4* Ks4 = (const float4*)Ks;
    float a00 = 0.f, a01 = 0.f, a10 = 0.f, a11 = 0.f;

#pragma unroll 4
    for (int c = 0; c < 32; ++c) {
        const float4 q0 = Qs4[ty * 33 + c];
        const float4 q1 = Qs4[(ty + 16) * 33 + c];
        const float4 k0 = Ks4[tx * 33 + c];
        const float4 k1 = Ks4[(tx + 16) * 33 + c];
        a00 = fmaf(q0.x, k0.x, a00); a00 = fmaf(q0.y, k0.y, a00); a00 = fmaf(q0.z, k0.z, a00); a00 = fmaf(q0.w, k0.w, a00);
        a01 = fmaf(q0.x, k1.x, a01); a01 = fmaf(q0.y, k1.y, a01); a01 = fmaf(q0.z, k1.z, a01); a01 = fmaf(q0.w, k1.w, a01);
        a10 = fmaf(q1.x, k0.x, a10); a10 = fmaf(q1.y, k0.y, a10); a10 = fmaf(q1.z, k0.z, a10); a10 = fmaf(q1.w, k0.w, a10);
        a11 = fmaf(q1.x, k1.x, a11); a11 = fmaf(q1.y, k1.y, a11); a11 = fmaf(q1.z, k1.z, a11); a11 = fmaf(q1.w, k1.w, a11);
    }

    const int i0 = bi + ty, i1 = bi + ty + 16;
    const int j0 = bj + tx, j1 = bj + tx + 16;
    S[(size_t)i0 * N + j0] = a00 * __expf(-dist[(size_t)i0 * N + j0]);
    S[(size_t)i0 * N + j1] = a01 * __expf(-dist[(size_t)i0 * N + j1]);
    S[(size_t)i1 * N + j0] = a10 * __expf(-dist[(size_t)i1 * N + j0]);
    S[(size_t)i1 * N + j1] = a11 * __expf(-dist[(size_t)i1 * N + j1]);
}

// ---------------- softmax + top-32 per row; one wave per row, no barriers ----------------
__global__ __launch_bounds__(256) void topk_kernel(float* buf /* in: scores, out: adjacency (in-place) */)
{
    const int lane = threadIdx.x & 63;
    const int row  = blockIdx.x * 4 + (threadIdx.x >> 6);
    float* sr = buf + (size_t)row * N;

    float v[16];
#pragma unroll
    for (int c = 0; c < 4; ++c) {
        const float4 f = *(const float4*)&sr[(c * 64 + lane) * 4];
        v[c * 4 + 0] = f.x; v[c * 4 + 1] = f.y; v[c * 4 + 2] = f.z; v[c * 4 + 3] = f.w;
    }
    float m = v[0];
#pragma unroll
    for (int e = 1; e < 16; ++e) m = fmaxf(m, v[e]);
#pragma unroll
    for (int off = 1; off < 64; off <<= 1) m = fmaxf(m, __shfl_xor(m, off));
    float sum = 0.f;
#pragma unroll
    for (int e = 0; e < 16; ++e) sum += __expf(v[e] - m);
#pragma unroll
    for (int off = 1; off < 64; off <<= 1) sum += __shfl_xor(sum, off);
    const float inv = 1.0f / sum;

    // 64-bit keys: monotonic-float high word, inverted index low word (ties -> smallest j, = lax.top_k)
    unsigned long long key[16];
#pragma unroll
    for (int e = 0; e < 16; ++e) {
        const int j = (((e >> 2) * 64 + lane) * 4) + (e & 3);
        unsigned u = __float_as_uint(v[e]);
        u = (u & 0x80000000u) ? ~u : (u | 0x80000000u);
        key[e] = ((unsigned long long)u << 32) | (unsigned)(N - 1 - j);
    }
    unsigned flags = 0;
    for (int it = 0; it < 32; ++it) {
        unsigned long long best = key[0];
#pragma unroll
        for (int e = 1; e < 16; ++e) best = (key[e] > best) ? key[e] : best;
#pragma unroll
        for (int off = 1; off < 64; off <<= 1) {
            const unsigned long long o = __shfl_xor(best, off);
            if (o > best) best = o;
        }
#pragma unroll
        for (int e = 0; e < 16; ++e)
            if (key[e] == best) { flags |= 1u << e; key[e] = 0ull; }
    }
#pragma unroll
    for (int c = 0; c < 4; ++c) {
        float4 o;
        o.x = (flags & (1u << (c * 4 + 0))) ? __expf(v[c * 4 + 0] - m) * inv : 0.f;
        o.y = (flags & (1u << (c * 4 + 1))) ? __expf(v[c * 4 + 1] - m) * inv : 0.f;
        o.z = (flags & (1u << (c * 4 + 2))) ? __expf(v[c * 4 + 2] - m) * inv : 0.f;
        o.w = (flags & (1u << (c * 4 + 3))) ? __expf(v[c * 4 + 3] - m) * inv : 0.f;
        *(float4*)&sr[(c * 64 + lane) * 4] = o;
    }
}

// ---------------- pairwise gelu classifier + 3-way softmax, 32x32 tile ----------------
__device__ __forceinline__ float fast_gelu(float x) {
    // x * sigmoid(1.5957691*x + 0.0713548*x^3) in exp2 form; max |err| vs exact gelu ~3e-4
    const float u = x * x;
    const float t = x * fmaf(-0.1029434f, u, -2.3022082f);
    return x * __builtin_amdgcn_rcpf(1.0f + __builtin_amdgcn_exp2f(t));
}

__global__ __launch_bounds__(256) void pair_kernel(
    const float* __restrict__ A, const float* __restrict__ B,
    const float* __restrict__ W2, const float* __restrict__ b2,
    float* __restrict__ out)
{
    __shared__ float As[32 * 33 * 4];
    __shared__ float Bs[32 * 33 * 4];
    __shared__ float Ws[3][132];           // W2 transposed; pitch 132 floats (16B-aligned rows)
    const int tid = threadIdx.x;
    const int bi = blockIdx.y * 32, bj = blockIdx.x * 32;
    const int tx = tid & 15, ty = tid >> 4;

#pragma unroll
    for (int t = 0; t < 4; ++t) {
        const int e = t * 256 + tid;
        const int row = e >> 5, c = e & 31;
        *(float4*)&As[(row * 33 + c) * 4] = *(const float4*)&A[(size_t)(bi + row) * D + c * 4];
        *(float4*)&Bs[(row * 33 + c) * 4] = *(const float4*)&B[(size_t)(bj + row) * D + c * 4];
    }
    if (tid < D) {
        Ws[0][tid] = W2[tid * 3 + 0];
        Ws[1][tid] = W2[tid * 3 + 1];
        Ws[2][tid] = W2[tid * 3 + 2];
    }
    const float bb0 = b2[0], bb1 = b2[1], bb2 = b2[2];
    __syncthreads();

    float l[4][3];
#pragma unroll
    for (int p = 0; p < 4; ++p) { l[p][0] = bb0; l[p][1] = bb1; l[p][2] = bb2; }

    const float4* As4 = (const float4*)As;
    const float4* Bs4 = (const float4*)Bs;

#pragma unroll 4
    for (int c = 0; c < 32; ++c) {
        const float4 a0 = As4[ty * 33 + c];
        const float4 a1 = As4[(ty + 16) * 33 + c];
        const float4 b0 = Bs4[tx * 33 + c];
        const float4 b1 = Bs4[(tx + 16) * 33 + c];
        const float4 w0 = *(const float4*)&Ws[0][c * 4];   // uniform -> LDS broadcast
        const float4 w1 = *(const float4*)&Ws[1][c * 4];
        const float4 w2 = *(const float4*)&Ws[2][c * 4];
#pragma unroll
        for (int q = 0; q < 4; ++q) {
            const float av0 = (q == 0) ? a0.x : (q == 1) ? a0.y : (q == 2) ? a0.z : a0.w;
            const float av1 = (q == 0) ? a1.x : (q == 1) ? a1.y : (q == 2) ? a1.z : a1.w;
            const float bv0 = (q == 0) ? b0.x : (q == 1) ? b0.y : (q == 2) ? b0.z : b0.w;
            const float bv1 = (q == 0) ? b1.x : (q == 1) ? b1.y : (q == 2) ? b1.z : b1.w;
            const float u0 = (q == 0) ? w0.x : (q == 1) ? w0.y : (q == 2) ? w0.z : w0.w;
            const float u1 = (q == 0) ? w1.x : (q == 1) ? w1.y : (q == 2) ? w1.z : w1.w;
            const float u2 = (q == 0) ? w2.x : (q == 1) ? w2.y : (q == 2) ? w2.z : w2.w;
            const float g00 = fast_gelu(av0 + bv0);
            const float g01 = fast_gelu(av0 + bv1);
            const float g10 = fast_gelu(av1 + bv0);
            const float g11 = fast_gelu(av1 + bv1);
            l[0][0] = fmaf(g00, u0, l[0][0]); l[0][1] = fmaf(g00, u1, l[0][1]); l[0][2] = fmaf(g00, u2, l[0][2]);
            l[1][0] = fmaf(g01, u0, l[1][0]); l[1][1] = fmaf(g01, u1, l[1][1]); l[1][2] = fmaf(g01, u2, l[1][2]);
            l[2][0] = fmaf(g10, u0, l[2][0]); l[2][1] = fmaf(g10, u1, l[2][1]); l[2][2] = fmaf(g10, u2, l[2][2]);
            l[3][0] = fmaf(g11, u0, l[3][0]); l[3][1] = fmaf(g11, u1, l[3][1]); l[3][2] = fmaf(g11, u2, l[3][2]);
        }
    }
#pragma unroll
    for (int p = 0; p < 4; ++p) {
        const int i = bi + ty + ((p & 2) ? 16 : 0);
        const int j = bj + tx + ((p & 1) ? 16 : 0);
        const float mm = fmaxf(l[p][0], fmaxf(l[p][1], l[p][2]));
        const float e0 = __expf(l[p][0] - mm), e1 = __expf(l[p][1] - mm), e2 = __expf(l[p][2] - mm);
        const float inv2 = 1.0f / (e0 + e1 + e2);
        float* o = out + ((size_t)i * N + j) * 3;
        o[0] = e0 * inv2; o[1] = e1 * inv2; o[2] = e2 * inv2;
    }
}

extern "C" void kernel_launch(void* const* d_in, const int* in_sizes, int n_in,
                              void* d_out, int out_size, void* d_ws, size_t ws_size,
                              hipStream_t stream)
{
    const float* z    = (const float*)d_in[0];
    const float* dist = (const float*)d_in[1];
    const float* Wq   = (const float*)d_in[2];
    const float* bq   = (const float*)d_in[3];
    const float* Wk   = (const float*)d_in[4];
    const float* bk   = (const float*)d_in[5];
    const float* W1   = (const float*)d_in[6];
    const float* b1   = (const float*)d_in[7];
    const float* W2   = (const float*)d_in[8];
    const float* b2   = (const float*)d_in[9];

    float* out = (float*)d_out;
    float* ws  = (float*)d_ws;
    float* Q  = ws;
    float* K  = ws + (size_t)N * D;
    float* A  = ws + 2 * (size_t)N * D;
    float* B  = ws + 3 * (size_t)N * D;

    proj_kernel<<<N / 8, 256, 0, stream>>>(z, Wq, bq, Wk, bk, W1, b1, Q, K, A, B);
    score_kernel<<<dim3(N / 32, N / 32), 256, 0, stream>>>(Q, K, dist, out);
    topk_kernel<<<N / 4, 256, 0, stream>>>(out);
    pair_kernel<<<dim3(N / 32, N / 32), 256, 0, stream>>>(A, B, W2, b2, out + (size_t)N * N);
}

// Round 5
// 166.000 us; speedup vs baseline: 1.7417x; 1.0072x over previous
//
#include <hip/hip_runtime.h>

#define N 1024
#define D 128

// ---------------- proj: Q,K,A,B = z@{Wq,Wk,W1a,W1b} (+biases; b1 folded into A; 1/sqrt(D) folded into Q) ----------------
__global__ __launch_bounds__(256) void proj_kernel(
    const float* __restrict__ z,
    const float* __restrict__ Wq, const float* __restrict__ bq,
    const float* __restrict__ Wk, const float* __restrict__ bk,
    const float* __restrict__ W1, const float* __restrict__ b1,
    float* __restrict__ Q, float* __restrict__ Kx,
    float* __restrict__ A, float* __restrict__ B)
{
    const int d  = threadIdx.x & (D - 1);
    const int h  = threadIdx.x >> 7;              // wave-uniform: 0 -> Q/K, 1 -> A/B
    const int r0 = blockIdx.x * 8;
    const float* __restrict__ Wa = h ? W1           : Wq;
    const float* __restrict__ Wb = h ? (W1 + D * D) : Wk;

    float acc0[8] = {0,0,0,0,0,0,0,0};
    float acc1[8] = {0,0,0,0,0,0,0,0};

    for (int c = 0; c < D / 4; ++c) {
        float4 zr[8];
#pragma unroll
        for (int r = 0; r < 8; ++r)
            zr[r] = *(const float4*)&z[(r0 + r) * D + c * 4];   // uniform addr -> scalar loads
#pragma unroll
        for (int q = 0; q < 4; ++q) {
            const int k = c * 4 + q;
            const float wa = Wa[k * D + d];
            const float wb = Wb[k * D + d];
#pragma unroll
            for (int r = 0; r < 8; ++r) {
                const float zv = (q == 0) ? zr[r].x : (q == 1) ? zr[r].y : (q == 2) ? zr[r].z : zr[r].w;
                acc0[r] = fmaf(zv, wa, acc0[r]);
                acc1[r] = fmaf(zv, wb, acc1[r]);
            }
        }
    }
    if (h == 0) {
        const float c0 = bq[d], c1 = bk[d];
        const float scale = 0.08838834764831845f;   // 1/sqrt(128), folded into Q
#pragma unroll
        for (int r = 0; r < 8; ++r) {
            Q [(r0 + r) * D + d] = (acc0[r] + c0) * scale;
            Kx[(r0 + r) * D + d] = acc1[r] + c1;
        }
    } else {
        const float c0 = b1[d];
#pragma unroll
        for (int r = 0; r < 8; ++r) {
            A[(r0 + r) * D + d] = acc0[r] + c0;
            B[(r0 + r) * D + d] = acc1[r];
        }
    }
}

// ---------------- scores: S = (Q K^T) * exp(-dist), 32x32 tile ----------------
__global__ __launch_bounds__(256) void score_kernel(
    const float* __restrict__ Q, const float* __restrict__ Kx,
    const float* __restrict__ dist, float* __restrict__ S)
{
    __shared__ float Qs[32 * 33 * 4];
    __shared__ float Ks[32 * 33 * 4];
    const int tid = threadIdx.x;
    const int bi = blockIdx.y * 32, bj = blockIdx.x * 32;
    const int tx = tid & 15, ty = tid >> 4;

#pragma unroll
    for (int t = 0; t < 4; ++t) {
        const int e = t * 256 + tid;           // 1024 chunks: 32 rows x 32 float4-cols
        const int row = e >> 5, c = e & 31;
        *(float4*)&Qs[(row * 33 + c) * 4] = *(const float4*)&Q [(size_t)(bi + row) * D + c * 4];
        *(float4*)&Ks[(row * 33 + c) * 4] = *(const float4*)&Kx[(size_t)(bj + row) * D + c * 4];
    }
    __syncthreads();

    const float4* Qs4 = (const float4*)Qs;
    const float4* Ks4 = (const float4*)Ks;
    float a00 = 0.f, a01 = 0.f, a10 = 0.f, a11 = 0.f;

#pragma unroll 4
    for (int c = 0; c < 32; ++c) {
        const float4 q0 = Qs4[ty * 33 + c];
        const float4 q1 = Qs4[(ty + 16) * 33 + c];
        const float4 k0 = Ks4[tx * 33 + c];
        const float4 k1 = Ks4[(tx + 16) * 33 + c];
        a00 = fmaf(q0.x, k0.x, a00); a00 = fmaf(q0.y, k0.y, a00); a00 = fmaf(q0.z, k0.z, a00); a00 = fmaf(q0.w, k0.w, a00);
        a01 = fmaf(q0.x, k1.x, a01); a01 = fmaf(q0.y, k1.y, a01); a01 = fmaf(q0.z, k1.z, a01); a01 = fmaf(q0.w, k1.w, a01);
        a10 = fmaf(q1.x, k0.x, a10); a10 = fmaf(q1.y, k0.y, a10); a10 = fmaf(q1.z, k0.z, a10); a10 = fmaf(q1.w, k0.w, a10);
        a11 = fmaf(q1.x, k1.x, a11); a11 = fmaf(q1.y, k1.y, a11); a11 = fmaf(q1.z, k1.z, a11); a11 = fmaf(q1.w, k1.w, a11);
    }

    const int i0 = bi + ty, i1 = bi + ty + 16;
    const int j0 = bj + tx, j1 = bj + tx + 16;
    S[(size_t)i0 * N + j0] = a00 * __expf(-dist[(size_t)i0 * N + j0]);
    S[(size_t)i0 * N + j1] = a01 * __expf(-dist[(size_t)i0 * N + j1]);
    S[(size_t)i1 * N + j0] = a10 * __expf(-dist[(size_t)i1 * N + j0]);
    S[(size_t)i1 * N + j1] = a11 * __expf(-dist[(size_t)i1 * N + j1]);
}

// ---------------- softmax + top-32 per row; one wave per row, no barriers ----------------
__global__ __launch_bounds__(256) void topk_kernel(float* buf /* in: scores, out: adjacency (in-place) */)
{
    const int lane = threadIdx.x & 63;
    const int row  = blockIdx.x * 4 + (threadIdx.x >> 6);
    float* sr = buf + (size_t)row * N;

    float v[16];
#pragma unroll
    for (int c = 0; c < 4; ++c) {
        const float4 f = *(const float4*)&sr[(c * 64 + lane) * 4];
        v[c * 4 + 0] = f.x; v[c * 4 + 1] = f.y; v[c * 4 + 2] = f.z; v[c * 4 + 3] = f.w;
    }
    float m = v[0];
#pragma unroll
    for (int e = 1; e < 16; ++e) m = fmaxf(m, v[e]);
#pragma unroll
    for (int off = 1; off < 64; off <<= 1) m = fmaxf(m, __shfl_xor(m, off));
    float sum = 0.f;
#pragma unroll
    for (int e = 0; e < 16; ++e) sum += __expf(v[e] - m);
#pragma unroll
    for (int off = 1; off < 64; off <<= 1) sum += __shfl_xor(sum, off);
    const float inv = 1.0f / sum;

    // 64-bit keys: monotonic-float high word, inverted index low word (ties -> smallest j, = lax.top_k)
    unsigned long long key[16];
#pragma unroll
    for (int e = 0; e < 16; ++e) {
        const int j = (((e >> 2) * 64 + lane) * 4) + (e & 3);
        unsigned u = __float_as_uint(v[e]);
        u = (u & 0x80000000u) ? ~u : (u | 0x80000000u);
        key[e] = ((unsigned long long)u << 32) | (unsigned)(N - 1 - j);
    }
    unsigned flags = 0;
    for (int it = 0; it < 32; ++it) {
        unsigned long long best = key[0];
#pragma unroll
        for (int e = 1; e < 16; ++e) best = (key[e] > best) ? key[e] : best;
#pragma unroll
        for (int off = 1; off < 64; off <<= 1) {
            const unsigned long long o = __shfl_xor(best, off);
            if (o > best) best = o;
        }
#pragma unroll
        for (int e = 0; e < 16; ++e)
            if (key[e] == best) { flags |= 1u << e; key[e] = 0ull; }
    }
#pragma unroll
    for (int c = 0; c < 4; ++c) {
        float4 o;
        o.x = (flags & (1u << (c * 4 + 0))) ? __expf(v[c * 4 + 0] - m) * inv : 0.f;
        o.y = (flags & (1u << (c * 4 + 1))) ? __expf(v[c * 4 + 1] - m) * inv : 0.f;
        o.z = (flags & (1u << (c * 4 + 2))) ? __expf(v[c * 4 + 2] - m) * inv : 0.f;
        o.w = (flags & (1u << (c * 4 + 3))) ? __expf(v[c * 4 + 3] - m) * inv : 0.f;
        *(float4*)&sr[(c * 64 + lane) * 4] = o;
    }
}

// ---------------- pairwise gelu classifier + 3-way softmax, 64x32 tile, 4x2 micro-tile ----------------
__device__ __forceinline__ float fast_gelu(float x) {
    // x * sigmoid(1.5957691*x + 0.0713548*x^3) in exp2 form; max |err| vs exact gelu ~3e-4
    const float u = x * x;
    const float t = x * fmaf(-0.1029434f, u, -2.3022082f);
    return x * __builtin_amdgcn_rcpf(1.0f + __builtin_amdgcn_exp2f(t));
}

__global__ __launch_bounds__(256) void pair_kernel(
    const float* __restrict__ A, const float* __restrict__ B,
    const float* __restrict__ W2, const float* __restrict__ b2,
    float* __restrict__ out)
{
    __shared__ float As[64 * 33 * 4];      // 64 i-rows, pitch 33 float4
    __shared__ float Bs[32 * 33 * 4];      // 32 j-rows
    __shared__ float Ws[3][132];           // W2 transposed
    const int tid = threadIdx.x;
    const int bi = blockIdx.y * 64, bj = blockIdx.x * 32;
    const int tx = tid & 15, ty = tid >> 4;

#pragma unroll
    for (int t = 0; t < 8; ++t) {
        const int e = t * 256 + tid;       // 2048 = 64 rows x 32 float4-chunks
        const int row = e >> 5, c = e & 31;
        *(float4*)&As[(row * 33 + c) * 4] = *(const float4*)&A[(size_t)(bi + row) * D + c * 4];
    }
#pragma unroll
    for (int t = 0; t < 4; ++t) {
        const int e = t * 256 + tid;       // 1024 = 32 rows x 32 float4-chunks
        const int row = e >> 5, c = e & 31;
        *(float4*)&Bs[(row * 33 + c) * 4] = *(const float4*)&B[(size_t)(bj + row) * D + c * 4];
    }
    if (tid < D) {
        Ws[0][tid] = W2[tid * 3 + 0];
        Ws[1][tid] = W2[tid * 3 + 1];
        Ws[2][tid] = W2[tid * 3 + 2];
    }
    const float bb0 = b2[0], bb1 = b2[1], bb2 = b2[2];
    __syncthreads();

    float l[8][3];                         // [ik*2+jk][class]
#pragma unroll
    for (int p = 0; p < 8; ++p) { l[p][0] = bb0; l[p][1] = bb1; l[p][2] = bb2; }

    const float4* As4 = (const float4*)As;
    const float4* Bs4 = (const float4*)Bs;

#pragma unroll 4
    for (int c = 0; c < 32; ++c) {
        float4 a[4], b[2];
#pragma unroll
        for (int k = 0; k < 4; ++k) a[k] = As4[(ty + 16 * k) * 33 + c];
        b[0] = Bs4[tx * 33 + c];
        b[1] = Bs4[(tx + 16) * 33 + c];
        const float4 w0 = *(const float4*)&Ws[0][c * 4];
        const float4 w1 = *(const float4*)&Ws[1][c * 4];
        const float4 w2 = *(const float4*)&Ws[2][c * 4];
#pragma unroll
        for (int q = 0; q < 4; ++q) {
            const float u0 = (q == 0) ? w0.x : (q == 1) ? w0.y : (q == 2) ? w0.z : w0.w;
            const float u1 = (q == 0) ? w1.x : (q == 1) ? w1.y : (q == 2) ? w1.z : w1.w;
            const float u2 = (q == 0) ? w2.x : (q == 1) ? w2.y : (q == 2) ? w2.z : w2.w;
            float bv[2];
            bv[0] = (q == 0) ? b[0].x : (q == 1) ? b[0].y : (q == 2) ? b[0].z : b[0].w;
            bv[1] = (q == 0) ? b[1].x : (q == 1) ? b[1].y : (q == 2) ? b[1].z : b[1].w;
#pragma unroll
            for (int k = 0; k < 4; ++k) {
                const float av = (q == 0) ? a[k].x : (q == 1) ? a[k].y : (q == 2) ? a[k].z : a[k].w;
#pragma unroll
                for (int j = 0; j < 2; ++j) {
                    const float g = fast_gelu(av + bv[j]);
                    const int p = k * 2 + j;
                    l[p][0] = fmaf(g, u0, l[p][0]);
                    l[p][1] = fmaf(g, u1, l[p][1]);
                    l[p][2] = fmaf(g, u2, l[p][2]);
                }
            }
        }
    }
#pragma unroll
    for (int k = 0; k < 4; ++k)
#pragma unroll
        for (int j = 0; j < 2; ++j) {
            const int p = k * 2 + j;
            const int i  = bi + ty + 16 * k;
            const int jj = bj + tx + 16 * j;
            const float mm = fmaxf(l[p][0], fmaxf(l[p][1], l[p][2]));
            const float e0 = __expf(l[p][0] - mm), e1 = __expf(l[p][1] - mm), e2 = __expf(l[p][2] - mm);
            const float inv2 = 1.0f / (e0 + e1 + e2);
            float* o = out + ((size_t)i * N + jj) * 3;
            o[0] = e0 * inv2; o[1] = e1 * inv2; o[2] = e2 * inv2;
        }
}

extern "C" void kernel_launch(void* const* d_in, const int* in_sizes, int n_in,
                              void* d_out, int out_size, void* d_ws, size_t ws_size,
                              hipStream_t stream)
{
    const float* z    = (const float*)d_in[0];
    const float* dist = (const float*)d_in[1];
    const float* Wq   = (const float*)d_in[2];
    const float* bq   = (const float*)d_in[3];
    const float* Wk   = (const float*)d_in[4];
    const float* bk   = (const float*)d_in[5];
    const float* W1   = (const float*)d_in[6];
    const float* b1   = (const float*)d_in[7];
    const float* W2   = (const float*)d_in[8];
    const float* b2   = (const float*)d_in[9];

    float* out = (float*)d_out;
    float* ws  = (float*)d_ws;
    float* Q  = ws;
    float* K  = ws + (size_t)N * D;
    float* A  = ws + 2 * (size_t)N * D;
    float* B  = ws + 3 * (size_t)N * D;

    proj_kernel<<<N / 8, 256, 0, stream>>>(z, Wq, bq, Wk, bk, W1, b1, Q, K, A, B);
    score_kernel<<<dim3(N / 32, N / 32), 256, 0, stream>>>(Q, K, dist, out);
    topk_kernel<<<N / 4, 256, 0, stream>>>(out);
    pair_kernel<<<dim3(N / 32, N / 64), 256, 0, stream>>>(A, B, W2, b2, out + (size_t)N * N);
}